// Round 1
// baseline (249.125 us; speedup 1.0000x reference)
//
#include <hip/hip_runtime.h>
#include <hip/hip_bf16.h>

typedef unsigned short u16;
typedef float  f32x4  __attribute__((ext_vector_type(4)));
typedef __bf16 bf16x8 __attribute__((ext_vector_type(8)));
typedef unsigned short u16x8 __attribute__((ext_vector_type(8)));

__device__ __forceinline__ u16 f2bfu(float f) {
    __hip_bfloat16 h = __float2bfloat16(f);
    return __builtin_bit_cast(unsigned short, h);
}

constexpr int kHW = 196;        // 14*14
constexpr int kNP = kHW * kHW;  // 38416 pairs per batch
constexpr int kC  = 256;

// ---------------- zero output ----------------
__global__ void k_zero(float* out) {
    out[blockIdx.x * 256 + threadIdx.x] = 0.f;
}

// ---------------- fp32 64x64 tile transpose: out[c][r] = in[r][c] ----------------
__global__ void k_tr_f32(const float* __restrict__ in, float* __restrict__ out,
                         int R, int Ccols) {
    __shared__ float t[64][65];
    int c0 = blockIdx.x * 64, r0 = blockIdx.y * 64;
    int lc = threadIdx.x & 63, lg = threadIdx.x >> 6;
#pragma unroll
    for (int rr = 0; rr < 16; ++rr) {
        int r = lg * 16 + rr;
        t[r][lc] = in[(r0 + r) * Ccols + c0 + lc];
    }
    __syncthreads();
#pragma unroll
    for (int rr = 0; rr < 16; ++rr) {
        int r = lg * 16 + rr;
        out[(c0 + r) * R + r0 + lc] = t[lc][r];
    }
}

// ---------------- fp32 -> bf16 transpose ----------------
__global__ void k_tr_bf16(const float* __restrict__ in, u16* __restrict__ out,
                          int R, int Ccols) {
    __shared__ float t[64][65];
    int c0 = blockIdx.x * 64, r0 = blockIdx.y * 64;
    int lc = threadIdx.x & 63, lg = threadIdx.x >> 6;
#pragma unroll
    for (int rr = 0; rr < 16; ++rr) {
        int r = lg * 16 + rr;
        t[r][lc] = in[(r0 + r) * Ccols + c0 + lc];
    }
    __syncthreads();
#pragma unroll
    for (int rr = 0; rr < 16; ++rr) {
        int r = lg * 16 + rr;
        out[(c0 + r) * R + r0 + lc] = f2bfu(t[lc][r]);
    }
}

// ---------------- xf[b][p][c] = sum_i im[b][i][p] * pwT[i][c] + pb[c] ----------------
// grid (25, 8), block 512. 8 p's per block.
__global__ __launch_bounds__(512)
void k_xf(const float* __restrict__ im, const float* __restrict__ pwT,
          const float* __restrict__ pb, float* __restrict__ xf) {
    __shared__ float sm[512 * 8];
    const int tid = threadIdx.x;
    const int b = blockIdx.y;
    const int p0 = blockIdx.x * 8;
#pragma unroll
    for (int it = 0; it < 8; ++it) {
        int idx = it * 512 + tid;
        int i = idx >> 3, pi = idx & 7;
        int p = p0 + pi;
        float v = 0.f;
        if (p < kHW) v = im[(b * 512 + i) * kHW + p];
        sm[idx] = v;  // layout [i][pi]
    }
    __syncthreads();
    const int c = tid & 255;
    const int half = tid >> 8;
    float acc[8] = {};
    const int ibase = half * 256;
    for (int k = 0; k < 256; ++k) {
        int i = ibase + k;
        float w = pwT[(i << 8) + c];             // coalesced across lanes
        f32x4 x0 = *(const f32x4*)&sm[i * 8];    // broadcast
        f32x4 x1 = *(const f32x4*)&sm[i * 8 + 4];
#pragma unroll
        for (int j = 0; j < 4; ++j) { acc[j] += x0[j] * w; acc[4 + j] += x1[j] * w; }
    }
    __syncthreads();
    if (half == 1) {
#pragma unroll
        for (int pi = 0; pi < 8; ++pi) sm[pi * 256 + c] = acc[pi];
    }
    __syncthreads();
    if (half == 0) {
        float bias = pb[c];
#pragma unroll
        for (int pi = 0; pi < 8; ++pi) {
            int p = p0 + pi;
            if (p < kHW)
                xf[((b * kHW + p) << 8) + c] = acc[pi] + sm[pi * 256 + c] + bias;
        }
    }
}

// ---------------- al[b][p][c] = xf[b][p][:] @ w1[0:256, c]; ak uses w1[256:512, c] ----
// grid (25, 8), block 512. 8 p's per block; threads 0..255 -> al, 256..511 -> ak.
__global__ __launch_bounds__(512)
void k_af(const float* __restrict__ xf, const float* __restrict__ w1,
          float* __restrict__ al, float* __restrict__ ak) {
    __shared__ float sm[256 * 8];
    const int tid = threadIdx.x;
    const int b = blockIdx.y;
    const int p0 = blockIdx.x * 8;
#pragma unroll
    for (int it = 0; it < 4; ++it) {
        int idx = it * 512 + tid;
        int k = idx >> 3, pi = idx & 7;
        int p = p0 + pi; if (p > kHW - 1) p = kHW - 1;
        sm[idx] = xf[((b * kHW + p) << 8) + k];  // layout [k][pi]
    }
    __syncthreads();
    const int c = tid & 255;
    const int sel = tid >> 8;
    const float* wbase = w1 + sel * 256 * 256;
    float acc[8] = {};
    for (int k = 0; k < 256; ++k) {
        float w = wbase[(k << 8) + c];           // coalesced
        f32x4 x0 = *(const f32x4*)&sm[k * 8];    // broadcast
        f32x4 x1 = *(const f32x4*)&sm[k * 8 + 4];
#pragma unroll
        for (int j = 0; j < 4; ++j) { acc[j] += x0[j] * w; acc[4 + j] += x1[j] * w; }
    }
    float* dst = sel ? ak : al;
#pragma unroll
    for (int pi = 0; pi < 8; ++pi) {
        int p = p0 + pi;
        if (p < kHW) dst[((b * kHW + p) << 8) + c] = acc[pi];
    }
}

// ---------------- main fused pair kernel ----------------
// grid (301, 8), block 512 (8 waves: 2 M x 4 N). Tile: 128 pairs x 256 channels.
__global__ __launch_bounds__(512, 4)
void k_main(const float* __restrict__ ak, const float* __restrict__ al,
            const float* __restrict__ b1, const u16* __restrict__ w2t,
            const float* __restrict__ b2, const u16* __restrict__ w3t,
            const float* __restrict__ b3, float* __restrict__ out) {
    __shared__ u16 smem[128 * 256];  // 64 KB: h1, then reused for h2
    const int tid = threadIdx.x;
    const int b = blockIdx.y;
    const int base = blockIdx.x * 128;

    // ---- stage 1: h1 = relu(ak[k] + al[l] + b1) -> bf16 in LDS (swizzled) ----
#pragma unroll
    for (int it = 0; it < 8; ++it) {
        int chunk = it * 512 + tid;
        int row = chunk >> 5;
        int cc = chunk & 31;
        int p = base + row;
        if (p > kNP - 1) p = kNP - 1;
        int ki = p / kHW;
        int li = p - ki * kHW;
        const float* akp = ak + ((b * kHW + ki) << 8) + (cc << 3);
        const float* alp = al + ((b * kHW + li) << 8) + (cc << 3);
        const float* b1p = b1 + (cc << 3);
        f32x4 k0 = *(const f32x4*)akp;
        f32x4 k1 = *(const f32x4*)(akp + 4);
        f32x4 l0 = *(const f32x4*)alp;
        f32x4 l1 = *(const f32x4*)(alp + 4);
        f32x4 c0 = *(const f32x4*)b1p;
        f32x4 c1 = *(const f32x4*)(b1p + 4);
        u16x8 v;
#pragma unroll
        for (int j = 0; j < 4; ++j) {
            v[j]     = f2bfu(fmaxf(k0[j] + l0[j] + c0[j], 0.f));
            v[4 + j] = f2bfu(fmaxf(k1[j] + l1[j] + c1[j], 0.f));
        }
        int byte = (row << 9) + (cc << 4);
        byte ^= (row & 7) << 4;
        *(u16x8*)((char*)smem + byte) = v;
    }
    __syncthreads();

    const int lane = tid & 63;
    const int wid = tid >> 6;
    const int wm = wid >> 2;   // 0..1 : rows
    const int wn = wid & 3;    // 0..3 : cols
    const int l15 = lane & 15;
    const int kg = lane >> 4;  // 0..3
    const int rowA = wm * 64 + l15;
    const int colB = wn * 64 + l15;

    // ---- GEMM1: h2 = relu(h1 @ w2 + b2) ----
    f32x4 acc[4][4] = {};
    for (int kk = 0; kk < 8; ++kk) {
        int kb = kk * 32 + kg * 8;
        bf16x8 a[4];
#pragma unroll
        for (int fm = 0; fm < 4; ++fm) {
            int row = rowA + fm * 16;
            int byte = (row << 9) + (kb << 1);
            byte ^= (row & 7) << 4;
            a[fm] = __builtin_bit_cast(bf16x8, *(const u16x8*)((const char*)smem + byte));
        }
#pragma unroll
        for (int fn = 0; fn < 4; ++fn) {
            bf16x8 bf = __builtin_bit_cast(
                bf16x8, *(const u16x8*)(w2t + ((colB + fn * 16) << 8) + kb));
#pragma unroll
            for (int fm = 0; fm < 4; ++fm)
                acc[fm][fn] = __builtin_amdgcn_mfma_f32_16x16x32_bf16(a[fm], bf, acc[fm][fn], 0, 0, 0);
        }
    }
    __syncthreads();
    // epilogue: h2 bf16 -> LDS (swizzled)
#pragma unroll
    for (int fn = 0; fn < 4; ++fn) {
        int col = colB + fn * 16;
        float bv = b2[col];
#pragma unroll
        for (int fm = 0; fm < 4; ++fm) {
#pragma unroll
            for (int r = 0; r < 4; ++r) {
                int row = wm * 64 + fm * 16 + kg * 4 + r;
                int byte = (row << 9) + (col << 1);
                byte ^= (row & 7) << 4;
                *(u16*)((char*)smem + byte) = f2bfu(fmaxf(acc[fm][fn][r] + bv, 0.f));
            }
        }
    }
    __syncthreads();

    // ---- GEMM2: h3 = relu(h2 @ w3 + b3), column-sum with row mask ----
    f32x4 acc2[4][4] = {};
    for (int kk = 0; kk < 8; ++kk) {
        int kb = kk * 32 + kg * 8;
        bf16x8 a[4];
#pragma unroll
        for (int fm = 0; fm < 4; ++fm) {
            int row = rowA + fm * 16;
            int byte = (row << 9) + (kb << 1);
            byte ^= (row & 7) << 4;
            a[fm] = __builtin_bit_cast(bf16x8, *(const u16x8*)((const char*)smem + byte));
        }
#pragma unroll
        for (int fn = 0; fn < 4; ++fn) {
            bf16x8 bf = __builtin_bit_cast(
                bf16x8, *(const u16x8*)(w3t + ((colB + fn * 16) << 8) + kb));
#pragma unroll
            for (int fm = 0; fm < 4; ++fm)
                acc2[fm][fn] = __builtin_amdgcn_mfma_f32_16x16x32_bf16(a[fm], bf, acc2[fm][fn], 0, 0, 0);
        }
    }

    float s[4] = {0.f, 0.f, 0.f, 0.f};
#pragma unroll
    for (int fn = 0; fn < 4; ++fn) {
        float bv = b3[colB + fn * 16];
#pragma unroll
        for (int fm = 0; fm < 4; ++fm) {
#pragma unroll
            for (int r = 0; r < 4; ++r) {
                int row = wm * 64 + fm * 16 + kg * 4 + r;
                if (base + row < kNP)
                    s[fn] += fmaxf(acc2[fm][fn][r] + bv, 0.f);
            }
        }
    }
#pragma unroll
    for (int fn = 0; fn < 4; ++fn) {
        s[fn] += __shfl_xor(s[fn], 16);
        s[fn] += __shfl_xor(s[fn], 32);
    }
    if (lane < 16) {
#pragma unroll
        for (int fn = 0; fn < 4; ++fn)
            atomicAdd(out + (b << 8) + wn * 64 + fn * 16 + lane, s[fn]);
    }
}

extern "C" void kernel_launch(void* const* d_in, const int* in_sizes, int n_in,
                              void* d_out, int out_size, void* d_ws, size_t ws_size,
                              hipStream_t stream) {
    const float* im = (const float*)d_in[0];
    const float* pw = (const float*)d_in[3];
    const float* pb = (const float*)d_in[4];
    const float* w1 = (const float*)d_in[5];
    const float* b1 = (const float*)d_in[6];
    const float* w2 = (const float*)d_in[7];
    const float* b2 = (const float*)d_in[8];
    const float* w3 = (const float*)d_in[9];
    const float* b3 = (const float*)d_in[10];
    float* out = (float*)d_out;

    float* xf  = (float*)d_ws;           // 8*196*256
    float* al  = xf + 8 * 196 * 256;
    float* ak  = al + 8 * 196 * 256;
    float* pwT = ak + 8 * 196 * 256;     // [512][256]
    u16* w2t = (u16*)(pwT + 512 * 256);  // [256][256] bf16, [n][k]
    u16* w3t = w2t + 256 * 256;

    hipLaunchKernelGGL(k_zero, dim3(8), dim3(256), 0, stream, out);
    hipLaunchKernelGGL(k_tr_f32, dim3(8, 4), dim3(256), 0, stream, pw, pwT, 256, 512);
    hipLaunchKernelGGL(k_tr_bf16, dim3(4, 4), dim3(256), 0, stream, w2, w2t, 256, 256);
    hipLaunchKernelGGL(k_tr_bf16, dim3(4, 4), dim3(256), 0, stream, w3, w3t, 256, 256);
    hipLaunchKernelGGL(k_xf, dim3(25, 8), dim3(512), 0, stream, im, pwT, pb, xf);
    hipLaunchKernelGGL(k_af, dim3(25, 8), dim3(512), 0, stream, xf, w1, al, ak);
    hipLaunchKernelGGL(k_main, dim3(301, 8), dim3(512), 0, stream, ak, al, b1, w2t, b2, w3t, b3, out);
}